// Round 7
// baseline (600.358 us; speedup 1.0000x reference)
//
#include <hip/hip_runtime.h>

// ---------------------------------------------------------------------------
// Fused MANN, R6: occupancy push on the R5 MFMA structure.
// R5 counters: 492us, MfmaUtil 14%, VALUBusy 15.5%, VGPR 188, LDS 72KB ->
// 2 waves/SIMD, latency-bound on L2 weight loads. Changes:
//  - 512-thread blocks (8 waves = 2 row-halves x 4 out-quarters), same 64-row
//    tile: 2 blocks/CU -> 16 waves/CU = 4 waves/SIMD IF VGPR <= 128.
//  - Register economy: 2 out-tiles/wave (acc 32 regs), '#pragma unroll 1' on
//    kc loops (R5's full unroll drove VGPR to 188 via load hoisting).
//  - ke-outer / kc-inner loops, blend folded once per ke in fp32.
// ---------------------------------------------------------------------------

typedef __attribute__((ext_vector_type(8))) short short8;
typedef __attribute__((ext_vector_type(4))) float f32x4;

constexpr int B_TOT = 131072;
constexpr int IN    = 256;
constexpr int HID   = 128;
constexpr int GH    = 64;
constexpr int NA    = 3;
constexpr int ROWS  = 64;
constexpr int XS    = 264;      // ushort stride of x tiles
constexpr int BS    = 132;      // f32 stride of layer3-input tile
constexpr float EPS = 1e-5f;

// ws layout (ushort element offsets); frag-major: [tile][kc][lane][8]
constexpr int O_G1H = 0;        // 4gt*8kc*64*8   = 16384
constexpr int O_E1H = 32768;    // 4ke*8ot*8kc*64*8 = 131072
constexpr int O_E2H = 294912;   // 4ke*8ot*4kc*64*8 = 65536

__device__ __forceinline__ unsigned short bf16h(float f) {
  unsigned int u = __float_as_uint(f);
  return (unsigned short)((u + 0x7FFFu + ((u >> 16) & 1u)) >> 16);  // RNE
}
__device__ __forceinline__ float bf16f(unsigned short h) {
  return __uint_as_float(((unsigned int)h) << 16);
}

// ---- prep: fp32 weights -> frag-major bf16 hi/lo in ws -------------------
__global__ __launch_bounds__(256) void prep_w(
    const float* __restrict__ gw1, const float* __restrict__ e1w,
    const float* __restrict__ e2w, unsigned short* __restrict__ ws)
{
  const int NT = 16384 + 131072 + 65536;
  for (int d = blockIdx.x * 256 + threadIdx.x; d < NT; d += gridDim.x * 256) {
    float v; int dst, lo_off;
    if (d < 16384) {
      int d2 = d; int j = d2 & 7, lane = (d2 >> 3) & 63, kc = (d2 >> 9) & 7, gt = d2 >> 12;
      int o = gt * 16 + (lane & 15), k = kc * 32 + (lane >> 4) * 8 + j;
      v = gw1[o * IN + k]; dst = O_G1H + d2; lo_off = 16384;
    } else if (d < 147456) {
      int d2 = d - 16384; int j = d2 & 7, lane = (d2 >> 3) & 63, kc = (d2 >> 9) & 7,
          ot = (d2 >> 12) & 7, ke = d2 >> 15;
      int o = ot * 16 + (lane & 15), k = kc * 32 + (lane >> 4) * 8 + j;
      v = e1w[ke * HID * IN + o * IN + k]; dst = O_E1H + d2; lo_off = 131072;
    } else {
      int d2 = d - 147456; int j = d2 & 7, lane = (d2 >> 3) & 63, kc = (d2 >> 9) & 3,
          ot = (d2 >> 11) & 7, ke = d2 >> 14;
      int o = ot * 16 + (lane & 15), k = kc * 32 + (lane >> 4) * 8 + j;
      v = e2w[ke * HID * HID + o * HID + k]; dst = O_E2H + d2; lo_off = 65536;
    }
    unsigned short h = bf16h(v);
    ws[dst] = h;
    ws[dst + lo_off] = bf16h(v - bf16f(h));
  }
}

#define MFMA(a, b, c) __builtin_amdgcn_mfma_f32_16x16x32_bf16((a), (b), (c), 0, 0, 0)

__global__ __launch_bounds__(512) void mann_mfma(
    const float* __restrict__ state,
    const float* __restrict__ gb1,
    const float* __restrict__ gln_g, const float* __restrict__ gln_b,
    const float* __restrict__ gw2, const float* __restrict__ gb2,
    const float* __restrict__ temperature,
    const float* __restrict__ e1_b,
    const float* __restrict__ ln1_g, const float* __restrict__ ln1_b,
    const float* __restrict__ e2_b,
    const float* __restrict__ ln2_g, const float* __restrict__ ln2_b,
    const float* __restrict__ e3_w, const float* __restrict__ e3_b,
    const unsigned short* __restrict__ wf,
    float* __restrict__ out_policy, float* __restrict__ out_blend)
{
  __shared__ __align__(16) unsigned char smem[75264];
  unsigned short* xh = (unsigned short*)smem;               // [64][264]
  unsigned short* xl = (unsigned short*)(smem + 33792);     // [64][264]
  unsigned short* ah = (unsigned short*)smem;               // overlay: [64][128] swz
  unsigned short* al = (unsigned short*)(smem + 16384);     // overlay: [64][128] swz
  float* bt    = (float*)(smem + 33792);                    // overlay: [64][132]
  float* ps    = (float*)(smem + 67584);                    // [64][4][2]
  float* stats = (float*)(smem + 69632);                    // [64][2]
  float* lp    = (float*)(smem + 70144);                    // [64][4][4]
  float* sbl   = (float*)(smem + 74240);                    // [64][4]

  const int tid = threadIdx.x;
  const int lane = tid & 63, wv = tid >> 6;      // 8 waves
  const int l15 = lane & 15, l4 = lane >> 4;
  const int rh = wv >> 2, oq = wv & 3;           // row-half, out-quarter
  const int rowbase = blockIdx.x * ROWS;
  const f32x4 zz = {0.f, 0.f, 0.f, 0.f};

  // ---- Phase A: stage x as bf16 hi/lo (coalesced float4 reads) ----
  {
    const float4* gsrc = (const float4*)(state + (size_t)rowbase * IN);
#pragma unroll
    for (int it = 0; it < 8; ++it) {
      int fi = tid + it * 512;
      int row = fi >> 6, c4 = fi & 63;
      float4 v = gsrc[fi];
      int base = row * XS + c4 * 4;
      float vv[4] = {v.x, v.y, v.z, v.w};
#pragma unroll
      for (int e = 0; e < 4; ++e) {
        unsigned short h = bf16h(vv[e]);
        xh[base + e] = h;
        xl[base + e] = bf16h(vv[e] - bf16f(h));
      }
    }
  }
  __syncthreads();

  // ---- Gating: each wave = (rh, oq): 1 out-tile of 16, 2 row-tiles ----
  {
    f32x4 g[2] = {zz, zz};
    const unsigned short* wpg = wf + O_G1H + (oq * 8 * 64 + (size_t)lane) * 8;
#pragma unroll 1
    for (int kc = 0; kc < 8; ++kc) {
      short8 wh = *(const short8*)(wpg + kc * 512);
      short8 wl = *(const short8*)(wpg + kc * 512 + 16384);
#pragma unroll
      for (int rt = 0; rt < 2; ++rt) {
        int row = rh * 32 + rt * 16 + l15;
        int xo = row * XS + kc * 32 + l4 * 8;
        short8 xhf = *(const short8*)&xh[xo];
        short8 xlf = *(const short8*)&xl[xo];
        g[rt] = MFMA(xhf, wh, g[rt]);
        g[rt] = MFMA(xlf, wh, g[rt]);
        g[rt] = MFMA(xhf, wl, g[rt]);
      }
    }
    const float bv = gb1[oq * 16 + l15];
#pragma unroll
    for (int rt = 0; rt < 2; ++rt)
#pragma unroll
      for (int r = 0; r < 4; ++r) {
        g[rt][r] += bv;
        float sv = g[rt][r], qv = g[rt][r] * g[rt][r];
#pragma unroll
        for (int m = 1; m < 16; m <<= 1) { sv += __shfl_xor(sv, m, 64); qv += __shfl_xor(qv, m, 64); }
        if (l15 == 0) {
          int row = rh * 32 + rt * 16 + l4 * 4 + r;
          ps[(row * 4 + oq) * 2 + 0] = sv;
          ps[(row * 4 + oq) * 2 + 1] = qv;
        }
      }
    __syncthreads();
    if (tid < 64) {
      float s = 0.f, q = 0.f;
#pragma unroll
      for (int o = 0; o < 4; ++o) { s += ps[(tid * 4 + o) * 2]; q += ps[(tid * 4 + o) * 2 + 1]; }
      float mu = s * (1.f / GH), var = q * (1.f / GH) - mu * mu;
      stats[tid * 2] = mu; stats[tid * 2 + 1] = rsqrtf(var + EPS);
    }
    __syncthreads();
    const float gg = gln_g[oq * 16 + l15], gbb = gln_b[oq * 16 + l15];
    float g2[4];
#pragma unroll
    for (int k = 0; k < 4; ++k) g2[k] = gw2[k * GH + oq * 16 + l15];
#pragma unroll
    for (int rt = 0; rt < 2; ++rt)
#pragma unroll
      for (int r = 0; r < 4; ++r) {
        int row = rh * 32 + rt * 16 + l4 * 4 + r;
        float mu = stats[row * 2], rstd = stats[row * 2 + 1];
        float h = fmaxf((g[rt][r] - mu) * rstd * gg + gbb, 0.f);
#pragma unroll
        for (int k = 0; k < 4; ++k) {
          float pv = h * g2[k];
#pragma unroll
          for (int m = 1; m < 16; m <<= 1) pv += __shfl_xor(pv, m, 64);
          if (l15 == 0) lp[(row * 4 + oq) * 4 + k] = pv;
        }
      }
  }
  __syncthreads();

  // ---- softmax -> blend ----
  if (tid < 256) {
    int row = tid >> 2, kk = tid & 3;
    float lg = lp[(row * 4 + 0) * 4 + kk] + lp[(row * 4 + 1) * 4 + kk] +
               lp[(row * 4 + 2) * 4 + kk] + lp[(row * 4 + 3) * 4 + kk] + gb2[kk];
    float t = fminf(fmaxf(temperature[0], 0.1f), 2.0f);
    lg /= t;
    float mx = lg;
    mx = fmaxf(mx, __shfl_xor(mx, 1, 64));
    mx = fmaxf(mx, __shfl_xor(mx, 2, 64));
    float e = expf(lg - mx);
    float su = e;
    su += __shfl_xor(su, 1, 64);
    su += __shfl_xor(su, 2, 64);
    float bl = e / su;
    sbl[row * 4 + kk] = bl;
    out_blend[(size_t)(rowbase + row) * 4 + kk] = bl;
  }
  __syncthreads();

  f32x4 accb[2][2] = {{zz, zz}, {zz, zz}};

  // ---- Layer 1 (256 -> 128): wave = 2 out-tiles (oq*32..+31), 2 row-tiles --
#pragma unroll
  for (int ke = 0; ke < 4; ++ke) {
    f32x4 t[2][2] = {{zz, zz}, {zz, zz}};
    const unsigned short* wp1 = wf + O_E1H + (((ke * 8 + oq * 2) * 8) * 64 + (size_t)lane) * 8;
    // ot stride 4096 ushorts, kc stride 512
#pragma unroll 1
    for (int kc = 0; kc < 8; ++kc) {
      short8 xhf[2], xlf[2];
#pragma unroll
      for (int rt = 0; rt < 2; ++rt) {
        int row = rh * 32 + rt * 16 + l15;
        int xo = row * XS + kc * 32 + l4 * 8;
        xhf[rt] = *(const short8*)&xh[xo];
        xlf[rt] = *(const short8*)&xl[xo];
      }
#pragma unroll
      for (int ot = 0; ot < 2; ++ot) {
        const unsigned short* p = wp1 + ot * 4096 + kc * 512;
        short8 wh = *(const short8*)p;
        short8 wl = *(const short8*)(p + 131072);
#pragma unroll
        for (int rt = 0; rt < 2; ++rt) {
          t[rt][ot] = MFMA(xhf[rt], wh, t[rt][ot]);
          t[rt][ot] = MFMA(xlf[rt], wh, t[rt][ot]);
          t[rt][ot] = MFMA(xhf[rt], wl, t[rt][ot]);
        }
      }
    }
    const float bv0 = e1_b[ke * HID + oq * 32 + l15];
    const float bv1 = e1_b[ke * HID + oq * 32 + 16 + l15];
#pragma unroll
    for (int rt = 0; rt < 2; ++rt)
#pragma unroll
      for (int r = 0; r < 4; ++r) {
        int row = rh * 32 + rt * 16 + l4 * 4 + r;
        float blv = sbl[row * 4 + ke];
        accb[rt][0][r] += blv * (t[rt][0][r] + bv0);
        accb[rt][1][r] += blv * (t[rt][1][r] + bv1);
      }
  }
  // L1 LN partials
#pragma unroll
  for (int rt = 0; rt < 2; ++rt)
#pragma unroll
    for (int r = 0; r < 4; ++r) {
      float sv = accb[rt][0][r] + accb[rt][1][r];
      float qv = accb[rt][0][r] * accb[rt][0][r] + accb[rt][1][r] * accb[rt][1][r];
#pragma unroll
      for (int m = 1; m < 16; m <<= 1) { sv += __shfl_xor(sv, m, 64); qv += __shfl_xor(qv, m, 64); }
      if (l15 == 0) {
        int row = rh * 32 + rt * 16 + l4 * 4 + r;
        ps[(row * 4 + oq) * 2 + 0] = sv;
        ps[(row * 4 + oq) * 2 + 1] = qv;
      }
    }
  __syncthreads();
  if (tid < 64) {
    float s = 0.f, q = 0.f;
#pragma unroll
    for (int o = 0; o < 4; ++o) { s += ps[(tid * 4 + o) * 2]; q += ps[(tid * 4 + o) * 2 + 1]; }
    float mu = s * (1.f / HID), var = q * (1.f / HID) - mu * mu;
    stats[tid * 2] = mu; stats[tid * 2 + 1] = rsqrtf(var + EPS);
  }
  __syncthreads();
  // L1 normalize -> ah/al (swizzled), overlays dead x tile
  {
#pragma unroll
    for (int ot = 0; ot < 2; ++ot) {
      int c = oq * 32 + ot * 16 + l15;
      float lgv = ln1_g[c], lbv = ln1_b[c];
#pragma unroll
      for (int rt = 0; rt < 2; ++rt)
#pragma unroll
        for (int r = 0; r < 4; ++r) {
          int row = rh * 32 + rt * 16 + l4 * 4 + r;
          float mu = stats[row * 2], rstd = stats[row * 2 + 1];
          float y = fmaxf((accb[rt][ot][r] - mu) * rstd * lgv + lbv, 0.f);
          unsigned short h = bf16h(y);
          int idx = row * HID + (((c >> 3) ^ (row & 7)) << 3) + (c & 7);
          ah[idx] = h; al[idx] = bf16h(y - bf16f(h));
        }
    }
  }
  __syncthreads();

  // ---- Layer 2 (128 -> 128) ----
#pragma unroll
  for (int rt = 0; rt < 2; ++rt)
#pragma unroll
    for (int ot = 0; ot < 2; ++ot) accb[rt][ot] = zz;
#pragma unroll
  for (int ke = 0; ke < 4; ++ke) {
    f32x4 t[2][2] = {{zz, zz}, {zz, zz}};
    const unsigned short* wp2 = wf + O_E2H + (((ke * 8 + oq * 2) * 4) * 64 + (size_t)lane) * 8;
    // ot stride 2048 ushorts, kc stride 512
#pragma unroll 1
    for (int kc = 0; kc < 4; ++kc) {
      short8 xhf[2], xlf[2];
#pragma unroll
      for (int rt = 0; rt < 2; ++rt) {
        int row = rh * 32 + rt * 16 + l15;
        int gidx = (kc * 4 + l4) ^ (row & 7);
        int idx = row * HID + gidx * 8;
        xhf[rt] = *(const short8*)&ah[idx];
        xlf[rt] = *(const short8*)&al[idx];
      }
#pragma unroll
      for (int ot = 0; ot < 2; ++ot) {
        const unsigned short* p = wp2 + ot * 2048 + kc * 512;
        short8 wh = *(const short8*)p;
        short8 wl = *(const short8*)(p + 65536);
#pragma unroll
        for (int rt = 0; rt < 2; ++rt) {
          t[rt][ot] = MFMA(xhf[rt], wh, t[rt][ot]);
          t[rt][ot] = MFMA(xlf[rt], wh, t[rt][ot]);
          t[rt][ot] = MFMA(xhf[rt], wl, t[rt][ot]);
        }
      }
    }
    const float bv0 = e2_b[ke * HID + oq * 32 + l15];
    const float bv1 = e2_b[ke * HID + oq * 32 + 16 + l15];
#pragma unroll
    for (int rt = 0; rt < 2; ++rt)
#pragma unroll
      for (int r = 0; r < 4; ++r) {
        int row = rh * 32 + rt * 16 + l4 * 4 + r;
        float blv = sbl[row * 4 + ke];
        accb[rt][0][r] += blv * (t[rt][0][r] + bv0);
        accb[rt][1][r] += blv * (t[rt][1][r] + bv1);
      }
  }
  // L2 LN partials
#pragma unroll
  for (int rt = 0; rt < 2; ++rt)
#pragma unroll
    for (int r = 0; r < 4; ++r) {
      float sv = accb[rt][0][r] + accb[rt][1][r];
      float qv = accb[rt][0][r] * accb[rt][0][r] + accb[rt][1][r] * accb[rt][1][r];
#pragma unroll
      for (int m = 1; m < 16; m <<= 1) { sv += __shfl_xor(sv, m, 64); qv += __shfl_xor(qv, m, 64); }
      if (l15 == 0) {
        int row = rh * 32 + rt * 16 + l4 * 4 + r;
        ps[(row * 4 + oq) * 2 + 0] = sv;
        ps[(row * 4 + oq) * 2 + 1] = qv;
      }
    }
  __syncthreads();
  if (tid < 64) {
    float s = 0.f, q = 0.f;
#pragma unroll
    for (int o = 0; o < 4; ++o) { s += ps[(tid * 4 + o) * 2]; q += ps[(tid * 4 + o) * 2 + 1]; }
    float mu = s * (1.f / HID), var = q * (1.f / HID) - mu * mu;
    stats[tid * 2] = mu; stats[tid * 2 + 1] = rsqrtf(var + EPS);
  }
  __syncthreads();
  // L2 normalize -> bt (fp32, overlays dead xl tile)
  {
#pragma unroll
    for (int ot = 0; ot < 2; ++ot) {
      int c = oq * 32 + ot * 16 + l15;
      float lgv = ln2_g[c], lbv = ln2_b[c];
#pragma unroll
      for (int rt = 0; rt < 2; ++rt)
#pragma unroll
        for (int r = 0; r < 4; ++r) {
          int row = rh * 32 + rt * 16 + l4 * 4 + r;
          float mu = stats[row * 2], rstd = stats[row * 2 + 1];
          float y = fmaxf((accb[rt][ot][r] - mu) * rstd * lgv + lbv, 0.f);
          bt[row * BS + c] = y;
        }
    }
  }
  __syncthreads();

  // ---- Layer 3 (128 -> 3) + blend reduce, VALU ----
  if (tid < 256) {
    int row = tid >> 2, kk = tid & 3;
    float p[NA] = {0.f, 0.f, 0.f};
#pragma unroll
    for (int ic = 0; ic < HID / 4; ++ic) {
      float4 xv = *(const float4*)&bt[row * BS + ic * 4];
#pragma unroll
      for (int a = 0; a < NA; ++a) {
        float4 wv = *(const float4*)&e3_w[(size_t)(kk * NA + a) * HID + ic * 4];
        p[a] = fmaf(xv.x, wv.x, fmaf(xv.y, wv.y, fmaf(xv.z, wv.z, fmaf(xv.w, wv.w, p[a]))));
      }
    }
    float blk = sbl[row * 4 + kk];
#pragma unroll
    for (int a = 0; a < NA; ++a) p[a] = blk * (p[a] + e3_b[kk * NA + a]);
#pragma unroll
    for (int a = 0; a < NA; ++a) {
      p[a] += __shfl_xor(p[a], 1, 64);
      p[a] += __shfl_xor(p[a], 2, 64);
    }
    if (kk == 0) {
      size_t o = (size_t)(rowbase + row) * NA;
      out_policy[o + 0] = p[0];
      out_policy[o + 1] = p[1];
      out_policy[o + 2] = p[2];
    }
  }
}

extern "C" void kernel_launch(void* const* d_in, const int* in_sizes, int n_in,
                              void* d_out, int out_size, void* d_ws, size_t ws_size,
                              hipStream_t stream) {
  const float* state = (const float*)d_in[0];
  const float* gw1   = (const float*)d_in[1];
  const float* gb1   = (const float*)d_in[2];
  const float* gln_g = (const float*)d_in[3];
  const float* gln_b = (const float*)d_in[4];
  const float* gw2   = (const float*)d_in[5];
  const float* gb2   = (const float*)d_in[6];
  const float* temp  = (const float*)d_in[7];
  const float* e1_w  = (const float*)d_in[8];
  const float* e1_b  = (const float*)d_in[9];
  const float* ln1_g = (const float*)d_in[10];
  const float* ln1_b = (const float*)d_in[11];
  const float* e2_w  = (const float*)d_in[12];
  const float* e2_b  = (const float*)d_in[13];
  const float* ln2_g = (const float*)d_in[14];
  const float* ln2_b = (const float*)d_in[15];
  const float* e3_w  = (const float*)d_in[16];
  const float* e3_b  = (const float*)d_in[17];

  unsigned short* wf = (unsigned short*)d_ws;
  float* out_policy = (float*)d_out;                       // [B,3]
  float* out_blend  = (float*)d_out + (size_t)B_TOT * NA;  // [B,4]

  prep_w<<<832, 256, 0, stream>>>(gw1, e1_w, e2_w, wf);
  mann_mfma<<<B_TOT / ROWS, 512, 0, stream>>>(
      state, gb1, gln_g, gln_b, gw2, gb2, temp,
      e1_b, ln1_g, ln1_b, e2_b, ln2_g, ln2_b, e3_w, e3_b,
      wf, out_policy, out_blend);
}

// Round 8
// 481.079 us; speedup vs baseline: 1.2479x; 1.2479x over previous
//
#include <hip/hip_runtime.h>

// ---------------------------------------------------------------------------
// Fused MANN, R7: occupancy-correct geometry.
// Evidence: R5 (72KB LDS) and R6 (75KB) both ran at ~1 block/CU (Occupancy
// 12%/21%); R1's 50688 B is the proven 3-blocks/CU point. LDS > 64KB appears
// to prevent co-residency. Changes vs R6:
//  - 48 rows/block, 512 thr, 8 waves = 8 distinct 16-col out-tiles, rt=3:
//    weight set (832 KB) loaded exactly once per block (no rh duplication).
//  - LDS 50304 B: x hi/lo [48][256] granule-XOR swizzle (no pad), LN stats
//    via ds_add_f32 atomics, logits/blend share one buffer.
//  - __launch_bounds__(512,6): VGPR<=85 -> 3 blocks/CU = 24 waves/CU.
//    Spill gate: WRITE_SIZE must stay ~3.6MB (R1 lesson).
// ---------------------------------------------------------------------------

typedef __attribute__((ext_vector_type(8))) short short8;
typedef __attribute__((ext_vector_type(4))) float f32x4;

constexpr int B_TOT = 131072;
constexpr int IN    = 256;
constexpr int HID   = 128;
constexpr int NA    = 3;
constexpr int ROWS  = 48;
constexpr float EPS = 1e-5f;

// ws layout (ushort element offsets); frag-major: [ke][ot][kc][lane][8]
// G1:[gt(4)][kc(8)] hi@0 lo@16384 ; E1:[ke(4)][ot(8)][kc(8)] hi@32768 lo@+131072
// E2:[ke(4)][ot(8)][kc(4)] hi@294912 lo@+65536 ; total 425984 ushorts = 832KB
__device__ __forceinline__ unsigned short bf16h(float f) {
  unsigned int u = __float_as_uint(f);
  return (unsigned short)((u + 0x7FFFu + ((u >> 16) & 1u)) >> 16);  // RNE
}
__device__ __forceinline__ float bf16f(unsigned short h) {
  return __uint_as_float(((unsigned int)h) << 16);
}

__global__ __launch_bounds__(256) void prep_w(
    const float* __restrict__ gw1, const float* __restrict__ e1w,
    const float* __restrict__ e2w, unsigned short* __restrict__ ws)
{
  const int NT = 16384 + 131072 + 65536;
  for (int d = blockIdx.x * 256 + threadIdx.x; d < NT; d += gridDim.x * 256) {
    float v; int dst, lo_off;
    if (d < 16384) {
      int d2 = d; int j = d2 & 7, lane = (d2 >> 3) & 63, kc = (d2 >> 9) & 7, gt = d2 >> 12;
      int o = gt * 16 + (lane & 15), k = kc * 32 + (lane >> 4) * 8 + j;
      v = gw1[o * IN + k]; dst = d2; lo_off = 16384;
    } else if (d < 147456) {
      int d2 = d - 16384; int j = d2 & 7, lane = (d2 >> 3) & 63, kc = (d2 >> 9) & 7,
          ot = (d2 >> 12) & 7, ke = d2 >> 15;
      int o = ot * 16 + (lane & 15), k = kc * 32 + (lane >> 4) * 8 + j;
      v = e1w[ke * HID * IN + o * IN + k]; dst = 32768 + d2; lo_off = 131072;
    } else {
      int d2 = d - 147456; int j = d2 & 7, lane = (d2 >> 3) & 63, kc = (d2 >> 9) & 3,
          ot = (d2 >> 11) & 7, ke = d2 >> 14;
      int o = ot * 16 + (lane & 15), k = kc * 32 + (lane >> 4) * 8 + j;
      v = e2w[ke * HID * HID + o * HID + k]; dst = 294912 + d2; lo_off = 65536;
    }
    unsigned short h = bf16h(v);
    ws[dst] = h;
    ws[dst + lo_off] = bf16h(v - bf16f(h));
  }
}

#define MFMA(a, b, c) __builtin_amdgcn_mfma_f32_16x16x32_bf16((a), (b), (c), 0, 0, 0)

__global__ __launch_bounds__(512, 6) void mann_mfma(
    const float* __restrict__ state,
    const float* __restrict__ gb1,
    const float* __restrict__ gln_g, const float* __restrict__ gln_b,
    const float* __restrict__ gw2, const float* __restrict__ gb2,
    const float* __restrict__ temperature,
    const float* __restrict__ e1_b,
    const float* __restrict__ ln1_g, const float* __restrict__ ln1_b,
    const float* __restrict__ e2_b,
    const float* __restrict__ ln2_g, const float* __restrict__ ln2_b,
    const float* __restrict__ e3_w, const float* __restrict__ e3_b,
    const unsigned short* __restrict__ wf,
    float* __restrict__ out_policy, float* __restrict__ out_blend)
{
  // 0      : xh [48][256] us (24576)   -> after L1: ah [48][128] @0, al @12288
  // 24576  : xl [48][256] us (24576)   -> after L2: bt [48][128] f32 (24576)
  // 49152  : stats f32[96] (384)
  // 49536  : logits/blend f32[192] (768)        total 50304 B
  __shared__ __align__(16) unsigned char smem[50304];
  unsigned short* xh = (unsigned short*)smem;
  unsigned short* xl = (unsigned short*)(smem + 24576);
  unsigned short* ah = (unsigned short*)smem;
  unsigned short* al = (unsigned short*)(smem + 12288);
  float* bt    = (float*)(smem + 24576);
  float* stats = (float*)(smem + 49152);
  float* sbl   = (float*)(smem + 49536);

  const int tid  = threadIdx.x;
  const int lane = tid & 63, wv = tid >> 6;     // 8 waves; wv = out-tile
  const int l15  = lane & 15, l4 = lane >> 4;
  const int rowbase = blockIdx.x * ROWS;
  const int valid = (B_TOT - rowbase) < ROWS ? (B_TOT - rowbase) : ROWS;
  const f32x4 zz = {0.f, 0.f, 0.f, 0.f};

  // ---- stage x as bf16 hi/lo, granule-XOR swizzled; zero stats+logits ----
  {
    const float4* gsrc = reinterpret_cast<const float4*>(state) + (size_t)rowbase * 64;
#pragma unroll
    for (int it = 0; it < 6; ++it) {
      int fi = tid + it * 512;              // 0..3071
      int row = fi >> 6, c4 = fi & 63;
      float4 v = {0.f, 0.f, 0.f, 0.f};
      if (row < valid) v = gsrc[fi];
      int g = c4 >> 1;                      // 16B granule 0..31
      int base = row * 256 + ((g ^ (row & 7)) << 3) + (c4 & 1) * 4;
      float vv[4] = {v.x, v.y, v.z, v.w};
#pragma unroll
      for (int e = 0; e < 4; ++e) {
        unsigned short h = bf16h(vv[e]);
        xh[base + e] = h;
        xl[base + e] = bf16h(vv[e] - bf16f(h));
      }
    }
    if (tid < 288) ((float*)(smem + 49152))[tid] = 0.f;
  }
  __syncthreads();                                               // B1

  // ---- gating MFMA (waves 0-3 = gate col-tiles), stats atomics ----
  f32x4 g[3] = {zz, zz, zz};
  if (wv < 4) {
    const unsigned short* wpg = wf + (size_t)wv * 4096 + lane * 8;
#pragma unroll 1
    for (int kc = 0; kc < 8; ++kc) {
      short8 wh = *(const short8*)(wpg + kc * 512);
      short8 wl = *(const short8*)(wpg + kc * 512 + 16384);
#pragma unroll
      for (int rt = 0; rt < 3; ++rt) {
        int row = rt * 16 + l15;
        int idx = row * 256 + (((kc * 4 + l4) ^ (row & 7)) << 3);
        short8 xhf = *(const short8*)&xh[idx];
        short8 xlf = *(const short8*)&xl[idx];
        g[rt] = MFMA(xhf, wh, g[rt]);
        g[rt] = MFMA(xlf, wh, g[rt]);
        g[rt] = MFMA(xhf, wl, g[rt]);
      }
    }
    const float bv = gb1[wv * 16 + l15];
#pragma unroll
    for (int rt = 0; rt < 3; ++rt)
#pragma unroll
      for (int r = 0; r < 4; ++r) {
        g[rt][r] += bv;
        float sv = g[rt][r], qv = g[rt][r] * g[rt][r];
#pragma unroll
        for (int m = 1; m < 16; m <<= 1) { sv += __shfl_xor(sv, m, 64); qv += __shfl_xor(qv, m, 64); }
        if (l15 == 0) {
          int row = rt * 16 + l4 * 4 + r;
          atomicAdd(&stats[row * 2 + 0], sv);
          atomicAdd(&stats[row * 2 + 1], qv);
        }
      }
  }
  __syncthreads();                                               // B2
  if (tid < ROWS) {
    float s = stats[tid * 2], q = stats[tid * 2 + 1];
    float mu = s * (1.f / 64.f), var = q * (1.f / 64.f) - mu * mu;
    stats[tid * 2] = mu; stats[tid * 2 + 1] = rsqrtf(var + EPS);
  }
  __syncthreads();                                               // B3
  if (wv < 4) {
    const float gg = gln_g[wv * 16 + l15], gbb = gln_b[wv * 16 + l15];
    float g2[4];
#pragma unroll
    for (int k = 0; k < 4; ++k) g2[k] = gw2[k * 64 + wv * 16 + l15];
#pragma unroll
    for (int rt = 0; rt < 3; ++rt)
#pragma unroll
      for (int r = 0; r < 4; ++r) {
        int row = rt * 16 + l4 * 4 + r;
        float mu = stats[row * 2], rstd = stats[row * 2 + 1];
        float h = fmaxf((g[rt][r] - mu) * rstd * gg + gbb, 0.f);
#pragma unroll
        for (int k = 0; k < 4; ++k) {
          float pv = h * g2[k];
#pragma unroll
          for (int m = 1; m < 16; m <<= 1) pv += __shfl_xor(pv, m, 64);
          if (l15 == 0) atomicAdd(&sbl[row * 4 + k], pv);
        }
      }
  }
  __syncthreads();                                               // B4
  // ---- softmax -> blend (overwrite logits in place); re-zero stats ----
  if (tid < ROWS * 4) {
    int row = tid >> 2, k = tid & 3;
    float lg = sbl[tid] + gb2[k];
    float tt = fminf(fmaxf(temperature[0], 0.1f), 2.0f);
    lg /= tt;
    float mx = lg;
    mx = fmaxf(mx, __shfl_xor(mx, 1, 64));
    mx = fmaxf(mx, __shfl_xor(mx, 2, 64));
    float e = expf(lg - mx);
    float su = e;
    su += __shfl_xor(su, 1, 64);
    su += __shfl_xor(su, 2, 64);
    float bl = e / su;
    sbl[tid] = bl;
    if (row < valid) out_blend[(size_t)(rowbase + row) * 4 + k] = bl;
  } else if (tid < 288) {
    stats[tid - 192] = 0.f;
  }
  __syncthreads();                                               // B5

  // ---- Layer 1 (256 -> 128): wave = out-tile wv, rt=3 ----
  f32x4 accb[3] = {zz, zz, zz};
#pragma unroll 1
  for (int ke = 0; ke < 4; ++ke) {
    f32x4 t[3] = {zz, zz, zz};
    const unsigned short* wp = wf + 32768 + (size_t)(ke * 8 + wv) * 4096 + lane * 8;
#pragma unroll 1
    for (int kc = 0; kc < 8; ++kc) {
      short8 wh = *(const short8*)(wp + kc * 512);
      short8 wl = *(const short8*)(wp + kc * 512 + 131072);
#pragma unroll
      for (int rt = 0; rt < 3; ++rt) {
        int row = rt * 16 + l15;
        int idx = row * 256 + (((kc * 4 + l4) ^ (row & 7)) << 3);
        short8 xhf = *(const short8*)&xh[idx];
        short8 xlf = *(const short8*)&xl[idx];
        t[rt] = MFMA(xhf, wh, t[rt]);
        t[rt] = MFMA(xlf, wh, t[rt]);
        t[rt] = MFMA(xhf, wl, t[rt]);
      }
    }
    const float bv = e1_b[ke * HID + wv * 16 + l15];
#pragma unroll
    for (int rt = 0; rt < 3; ++rt)
#pragma unroll
      for (int r = 0; r < 4; ++r) {
        int row = rt * 16 + l4 * 4 + r;
        float blv = sbl[row * 4 + ke];
        accb[rt][r] += blv * (t[rt][r] + bv);
      }
  }
#pragma unroll
  for (int rt = 0; rt < 3; ++rt)
#pragma unroll
    for (int r = 0; r < 4; ++r) {
      float sv = accb[rt][r], qv = accb[rt][r] * accb[rt][r];
#pragma unroll
      for (int m = 1; m < 16; m <<= 1) { sv += __shfl_xor(sv, m, 64); qv += __shfl_xor(qv, m, 64); }
      if (l15 == 0) {
        int row = rt * 16 + l4 * 4 + r;
        atomicAdd(&stats[row * 2 + 0], sv);
        atomicAdd(&stats[row * 2 + 1], qv);
      }
    }
  __syncthreads();                                               // B6
  if (tid < ROWS) {
    float s = stats[tid * 2], q = stats[tid * 2 + 1];
    float mu = s * (1.f / 128.f), var = q * (1.f / 128.f) - mu * mu;
    stats[tid * 2] = mu; stats[tid * 2 + 1] = rsqrtf(var + EPS);
  }
  __syncthreads();                                               // B7
  {
    const float lgv = ln1_g[wv * 16 + l15], lbv = ln1_b[wv * 16 + l15];
#pragma unroll
    for (int rt = 0; rt < 3; ++rt)
#pragma unroll
      for (int r = 0; r < 4; ++r) {
        int row = rt * 16 + l4 * 4 + r;
        float mu = stats[row * 2], rstd = stats[row * 2 + 1];
        float y = fmaxf((accb[rt][r] - mu) * rstd * lgv + lbv, 0.f);
        unsigned short h = bf16h(y);
        int g16 = (wv * 2 + (l15 >> 3)) ^ (row & 7);
        int idx = row * 128 + g16 * 8 + (l15 & 7);
        ah[idx] = h; al[idx] = bf16h(y - bf16f(h));
      }
  }
  __syncthreads();                                               // B8
  if (tid < 96) stats[tid] = 0.f;
  __syncthreads();                                               // B9

  // ---- Layer 2 (128 -> 128) ----
  accb[0] = zz; accb[1] = zz; accb[2] = zz;
#pragma unroll 1
  for (int ke = 0; ke < 4; ++ke) {
    f32x4 t[3] = {zz, zz, zz};
    const unsigned short* wp = wf + 294912 + (size_t)(ke * 8 + wv) * 2048 + lane * 8;
#pragma unroll 1
    for (int kc = 0; kc < 4; ++kc) {
      short8 wh = *(const short8*)(wp + kc * 512);
      short8 wl = *(const short8*)(wp + kc * 512 + 65536);
#pragma unroll
      for (int rt = 0; rt < 3; ++rt) {
        int row = rt * 16 + l15;
        int gi = (kc * 4 + l4) ^ (row & 7);
        int idx = row * 128 + gi * 8;
        short8 xhf = *(const short8*)&ah[idx];
        short8 xlf = *(const short8*)&al[idx];
        t[rt] = MFMA(xhf, wh, t[rt]);
        t[rt] = MFMA(xlf, wh, t[rt]);
        t[rt] = MFMA(xhf, wl, t[rt]);
      }
    }
    const float bv = e2_b[ke * HID + wv * 16 + l15];
#pragma unroll
    for (int rt = 0; rt < 3; ++rt)
#pragma unroll
      for (int r = 0; r < 4; ++r) {
        int row = rt * 16 + l4 * 4 + r;
        float blv = sbl[row * 4 + ke];
        accb[rt][r] += blv * (t[rt][r] + bv);
      }
  }
#pragma unroll
  for (int rt = 0; rt < 3; ++rt)
#pragma unroll
    for (int r = 0; r < 4; ++r) {
      float sv = accb[rt][r], qv = accb[rt][r] * accb[rt][r];
#pragma unroll
      for (int m = 1; m < 16; m <<= 1) { sv += __shfl_xor(sv, m, 64); qv += __shfl_xor(qv, m, 64); }
      if (l15 == 0) {
        int row = rt * 16 + l4 * 4 + r;
        atomicAdd(&stats[row * 2 + 0], sv);
        atomicAdd(&stats[row * 2 + 1], qv);
      }
    }
  __syncthreads();                                               // B10
  if (tid < ROWS) {
    float s = stats[tid * 2], q = stats[tid * 2 + 1];
    float mu = s * (1.f / 128.f), var = q * (1.f / 128.f) - mu * mu;
    stats[tid * 2] = mu; stats[tid * 2 + 1] = rsqrtf(var + EPS);
  }
  __syncthreads();                                               // B11
  {
    const float lgv = ln2_g[wv * 16 + l15], lbv = ln2_b[wv * 16 + l15];
#pragma unroll
    for (int rt = 0; rt < 3; ++rt)
#pragma unroll
      for (int r = 0; r < 4; ++r) {
        int row = rt * 16 + l4 * 4 + r;
        float mu = stats[row * 2], rstd = stats[row * 2 + 1];
        float y = fmaxf((accb[rt][r] - mu) * rstd * lgv + lbv, 0.f);
        int c = wv * 16 + l15;
        int gf = (wv * 4 + (l15 >> 2)) ^ (row & 7);
        bt[row * 128 + gf * 4 + (c & 3)] = y;
      }
  }
  __syncthreads();                                               // B12

  // ---- Layer 3 (128 -> 3) + blend reduce, VALU ----
  if (tid < ROWS * 4) {
    int row = tid >> 2, kk = tid & 3;
    float p0 = 0.f, p1 = 0.f, p2 = 0.f;
    const float* w3 = e3_w + (size_t)kk * NA * HID;
#pragma unroll 1
    for (int ic = 0; ic < 32; ++ic) {
      int gi = ic ^ (row & 7);
      float4 xv = *(const float4*)&bt[row * 128 + gi * 4];
      float4 w0 = *(const float4*)&w3[0 * HID + ic * 4];
      float4 w1 = *(const float4*)&w3[1 * HID + ic * 4];
      float4 w2 = *(const float4*)&w3[2 * HID + ic * 4];
      p0 = fmaf(xv.x, w0.x, fmaf(xv.y, w0.y, fmaf(xv.z, w0.z, fmaf(xv.w, w0.w, p0))));
      p1 = fmaf(xv.x, w1.x, fmaf(xv.y, w1.y, fmaf(xv.z, w1.z, fmaf(xv.w, w1.w, p1))));
      p2 = fmaf(xv.x, w2.x, fmaf(xv.y, w2.y, fmaf(xv.z, w2.z, fmaf(xv.w, w2.w, p2))));
    }
    float blk = sbl[row * 4 + kk];
    p0 = blk * (p0 + e3_b[kk * NA + 0]);
    p1 = blk * (p1 + e3_b[kk * NA + 1]);
    p2 = blk * (p2 + e3_b[kk * NA + 2]);
    p0 += __shfl_xor(p0, 1, 64); p0 += __shfl_xor(p0, 2, 64);
    p1 += __shfl_xor(p1, 1, 64); p1 += __shfl_xor(p1, 2, 64);
    p2 += __shfl_xor(p2, 1, 64); p2 += __shfl_xor(p2, 2, 64);
    if (kk == 0 && row < valid) {
      size_t o = (size_t)(rowbase + row) * NA;
      out_policy[o + 0] = p0;
      out_policy[o + 1] = p1;
      out_policy[o + 2] = p2;
    }
  }
}

extern "C" void kernel_launch(void* const* d_in, const int* in_sizes, int n_in,
                              void* d_out, int out_size, void* d_ws, size_t ws_size,
                              hipStream_t stream) {
  const float* state = (const float*)d_in[0];
  const float* gw1   = (const float*)d_in[1];
  const float* gb1   = (const float*)d_in[2];
  const float* gln_g = (const float*)d_in[3];
  const float* gln_b = (const float*)d_in[4];
  const float* gw2   = (const float*)d_in[5];
  const float* gb2   = (const float*)d_in[6];
  const float* temp  = (const float*)d_in[7];
  const float* e1_w  = (const float*)d_in[8];
  const float* e1_b  = (const float*)d_in[9];
  const float* ln1_g = (const float*)d_in[10];
  const float* ln1_b = (const float*)d_in[11];
  const float* e2_w  = (const float*)d_in[12];
  const float* e2_b  = (const float*)d_in[13];
  const float* ln2_g = (const float*)d_in[14];
  const float* ln2_b = (const float*)d_in[15];
  const float* e3_w  = (const float*)d_in[16];
  const float* e3_b  = (const float*)d_in[17];

  unsigned short* wf = (unsigned short*)d_ws;
  float* out_policy = (float*)d_out;                       // [B,3]
  float* out_blend  = (float*)d_out + (size_t)B_TOT * NA;  // [B,4]

  prep_w<<<832, 256, 0, stream>>>(gw1, e1_w, e2_w, wf);
  const int grid = (B_TOT + ROWS - 1) / ROWS;              // 2731
  mann_mfma<<<grid, 512, 0, stream>>>(
      state, gb1, gln_g, gln_b, gw2, gb2, temp,
      e1_b, ln1_g, ln1_b, e2_b, ln2_g, ln2_b, e3_w, e3_b,
      wf, out_policy, out_blend);
}